// Round 2
// baseline (387.882 us; speedup 1.0000x reference)
//
#include <hip/hip_runtime.h>
#include <hip/hip_bf16.h>

// Problem constants (fixed by setup_inputs)
#define N 8192
#define D 512
#define NBAGS 64
#define PER_BAG 128
#define TOPK 16

typedef float vfloat4 __attribute__((ext_vector_type(4)));

// ws layout (bytes):
//   invn    float[N]      @ 0       (32768)
//   keptIdx int[N*16]     @ 32768   (524288)
//   keptCnt int[N]        @ 557056  (32768)
//   deg     int[N]        @ 589824  (32768)
//   FW      float[64*512] @ 622592  (131072)
#define WS_INVN   0
#define WS_KIDX   32768
#define WS_KCNT   557056
#define WS_DEG    589824
#define WS_FW     622592

// Kernel 1 (v7): fused per-row inverse norm + FULL adj zero-fill.
// 2048 blocks x 256 thr. Block b: norms for rows 4b..4b+3 AND NT zero-fill
// of adj rows 4b..4b+3 (128 KB). No __syncthreads anywhere -> the NT store
// stream is unfenced and runs at fill-kernel BW (~6.3 TB/s, 256 MB ~= 42us),
// overlapping the 16 MB norm reads. Blocks 0..31 also zero deg[].
// R9 rationale: serial clean split. v6 (role-split blocks, concurrent)
// regressed +29us; v5 (interleaved stores between barriers) paid the
// __syncthreads vmcnt(0) drain. Here ALL bulk stores live in a kernel with
// zero barriers; simtopk keeps only its 4 MB window writes.
__global__ void norm_fill_kernel(const float* __restrict__ feat,
                                 float* __restrict__ invn,
                                 int* __restrict__ deg,
                                 float* __restrict__ adjOut) {
    int t = threadIdx.x;
    int b = blockIdx.x;
    if (b < 32) deg[b * 256 + t] = 0;
    int lane = t & 63, w = t >> 6;
    int r = b * 4 + w;
    const float4* fr = (const float4*)(feat + (size_t)r * D);
    float4 a = fr[lane];
    float4 bq = fr[lane + 64];
    float ss = a.x * a.x + a.y * a.y + a.z * a.z + a.w * a.w
             + bq.x * bq.x + bq.y * bq.y + bq.z * bq.z + bq.w * bq.w;
    #pragma unroll
    for (int off = 32; off > 0; off >>= 1) ss += __shfl_down(ss, off);
    if (lane == 0) invn[r] = 1.0f / fmaxf(sqrtf(ss), 1e-12f);
    // NT zero-fill: 4 adj rows = 8192 float4, 32 per thread.
    vfloat4 z = {0.f, 0.f, 0.f, 0.f};
    vfloat4* base = (vfloat4*)(adjOut + (size_t)b * 4 * N);
    #pragma unroll
    for (int j = 0; j < 32; ++j)
        __builtin_nontemporal_store(z, &base[t + 256 * j]);
}

// Kernel 2 (v7): LEAN sim + top-16. No bulk zero stores (done by kernel 1,
// stream-ordered before us). Only writes: 4 MB of window float4 + keptIdx/
// keptCnt + deg atomics. Barriers now guard pure LDS staging; the vmcnt(0)
// drain at each __syncthreads has only 17 cache-resident loads outstanding.
// Tile 8 rows x 128 cols, per-thread 1x4, grid (16,64), 4 blocks/CU.
__global__ __launch_bounds__(256, 4) void simtopk_kernel(
        const float* __restrict__ feat,
        const float* __restrict__ invn,
        float* __restrict__ adjOut,
        int* __restrict__ keptIdx,
        int* __restrict__ keptCnt,
        int* __restrict__ deg) {
    int rg = blockIdx.x;    // 0..15
    int bag = blockIdx.y;   // 0..63
    int t = threadIdx.x;    // 0..255
    __shared__ float colT[32][132];   // [k][c]  (b128 reads conflict-free)
    __shared__ float rowT[32][12];    // [k][r]
    int bagBase = bag * PER_BAG;
    int rowBase = bagBase + rg * 8;
    int tx = t & 31;        // cols 4tx..4tx+3
    int ty = t >> 5;        // 0..7 -> row ty
    float4 acc = make_float4(0.f, 0.f, 0.f, 0.f);

    int kk = t & 31;
    int sub = t >> 5;       // 0..7

    for (int it = 0; it < 16; ++it) {
        int k0 = it * 32;
        __syncthreads();
        #pragma unroll
        for (int c0 = 0; c0 < 16; ++c0) {
            int c = sub * 16 + c0;
            colT[kk][c] = feat[(size_t)(bagBase + c) * D + k0 + kk];
        }
        rowT[kk][sub] = feat[(size_t)(rowBase + sub) * D + k0 + kk];
        __syncthreads();
        // FMA over this chunk
        #pragma unroll
        for (int k = 0; k < 32; ++k) {
            float4 cv = *(const float4*)&colT[k][4 * tx];
            float rv = rowT[k][ty];
            acc.x += rv * cv.x; acc.y += rv * cv.y;
            acc.z += rv * cv.z; acc.w += rv * cv.w;
        }
    }
    // scale to cosine similarity
    float ic0 = invn[bagBase + 4 * tx];
    float ic1 = invn[bagBase + 4 * tx + 1];
    float ic2 = invn[bagBase + 4 * tx + 2];
    float ic3 = invn[bagBase + 4 * tx + 3];
    float ir = invn[rowBase + ty];
    acc.x *= ir * ic0; acc.y *= ir * ic1;
    acc.z *= ir * ic2; acc.w *= ir * ic3;

    // per-row top-16 within each half-wave (row ty);
    // 5-step shfl_xor butterfly, (val desc, idx asc) == lax.top_k tie-break
    {
        int r = rowBase + ty;
        float o0 = acc.x, o1 = acc.y, o2 = acc.z, o3 = acc.w;
        float w0 = o0, w1 = o1, w2 = o2, w3 = o3;
        int pm = 0, cnt = 0;
        #pragma unroll 1
        for (int itk = 0; itk < TOPK; ++itk) {
            float bv = w0; int bj = 0;
            if (w1 > bv) { bv = w1; bj = 1; }
            if (w2 > bv) { bv = w2; bj = 2; }
            if (w3 > bv) { bv = w3; bj = 3; }
            int bi = 4 * tx + bj;
            #pragma unroll
            for (int s = 1; s < 32; s <<= 1) {
                float ov = __shfl_xor(bv, s);
                int oi = __shfl_xor(bi, s);
                if (ov > bv || (ov == bv && oi < bi)) { bv = ov; bi = oi; }
            }
            if (bv <= 0.0f) break;   // uniform within half-wave
            if (tx == 0) keptIdx[(size_t)r * TOPK + cnt] = bi;
            cnt++;
            if ((bi >> 2) == tx) {
                pm |= 1 << (bi & 3);
                int q = bi & 3;
                if (q == 0) w0 = -1e30f;
                else if (q == 1) w1 = -1e30f;
                else if (q == 2) w2 = -1e30f;
                else w3 = -1e30f;
            }
        }
        if (tx == 0) keptCnt[r] = cnt;
        float4 ov4 = make_float4((pm & 1) ? o0 : 0.0f,
                                 (pm & 2) ? o1 : 0.0f,
                                 (pm & 4) ? o2 : 0.0f,
                                 (pm & 8) ? o3 : 0.0f);
        *(float4*)(adjOut + (size_t)r * N + bagBase + 4 * tx) = ov4;
        if (pm & 1) atomicAdd(&deg[bagBase + 4 * tx], 1);
        if (pm & 2) atomicAdd(&deg[bagBase + 4 * tx + 1], 1);
        if (pm & 4) atomicAdd(&deg[bagBase + 4 * tx + 2], 1);
        if (pm & 8) atomicAdd(&deg[bagBase + 4 * tx + 3], 1);
        int selfCol = rg * 8 + ty;
        if (tx == (selfCol >> 2) && !((pm >> (selfCol & 3)) & 1))
            atomicAdd(&deg[bagBase + selfCol], 1);
    }
}

// Kernel 3: w_r = dis[r]*sum_{c in C_r} dis[c]; FW[g,d] = sum_r w_r*feat[r,d]
// grid (64 bags, 4 d-chunks), 128 threads.
__global__ void wfw_kernel(const float* __restrict__ feat,
                           const int* __restrict__ keptIdx,
                           const int* __restrict__ keptCnt,
                           const int* __restrict__ deg,
                           float* __restrict__ FW) {
    int bag = blockIdx.x;
    int chunk = blockIdx.y;
    int t = threadIdx.x;            // 0..127
    __shared__ float wsh[PER_BAG];
    int bagBase = bag * PER_BAG;
    {
        int r = bagBase + t;
        int cnt = keptCnt[r];
        float sum = 0.0f;
        bool selfin = false;
        for (int k = 0; k < cnt; ++k) {
            int c = keptIdx[(size_t)r * TOPK + k];
            if (c == t) selfin = true;
            sum += rsqrtf((float)deg[bagBase + c]);
        }
        float disr = rsqrtf((float)deg[r]);
        if (!selfin) sum += disr;
        wsh[t] = disr * sum;
    }
    __syncthreads();
    int d = chunk * 128 + t;
    float acc = 0.0f;
    #pragma unroll 8
    for (int r = 0; r < PER_BAG; ++r)
        acc += wsh[r] * feat[(size_t)(bagBase + r) * D + d];
    FW[bag * D + d] = acc;
}

// Kernel 4: agg = FW @ W + 128*b.  grid (64, 2), 256 threads.
__global__ void agg_kernel(const float* __restrict__ FW,
                           const float* __restrict__ Wm,
                           const float* __restrict__ b,
                           float* __restrict__ aggOut) {
    int bag = blockIdx.x;
    int chunk = blockIdx.y;
    int t = threadIdx.x;
    __shared__ float fws[D];
    fws[t] = FW[bag * D + t];
    fws[256 + t] = FW[bag * D + 256 + t];
    __syncthreads();
    int d = chunk * 256 + t;
    float acc = 0.0f;
    #pragma unroll 8
    for (int k = 0; k < D; ++k)
        acc += fws[k] * Wm[(size_t)k * D + d];
    aggOut[bag * D + d] = acc + 128.0f * b[d];
}

extern "C" void kernel_launch(void* const* d_in, const int* in_sizes, int n_in,
                              void* d_out, int out_size, void* d_ws, size_t ws_size,
                              hipStream_t stream) {
    const float* feat = (const float*)d_in[0];
    const float* Wm   = (const float*)d_in[1];
    const float* b    = (const float*)d_in[2];
    // d_in[3] = batch (structure hardcoded: 64 contiguous bags x 128)
    // d_in[4] = n_topk (16), d_in[5] = n_bags (64)

    char* ws = (char*)d_ws;
    float* invn   = (float*)(ws + WS_INVN);
    int* keptIdx  = (int*)(ws + WS_KIDX);
    int* keptCnt  = (int*)(ws + WS_KCNT);
    int* deg      = (int*)(ws + WS_DEG);
    float* FW     = (float*)(ws + WS_FW);

    float* aggOut = (float*)d_out;                    // [64*512]
    float* adjOut = (float*)d_out + NBAGS * D;        // [8192*8192]

    norm_fill_kernel<<<N / 4, 256, 0, stream>>>(feat, invn, deg, adjOut);
    simtopk_kernel<<<dim3(16, NBAGS), 256, 0, stream>>>(feat, invn, adjOut,
                                                        keptIdx, keptCnt, deg);
    wfw_kernel<<<dim3(NBAGS, 4), PER_BAG, 0, stream>>>(feat, keptIdx, keptCnt,
                                                       deg, FW);
    agg_kernel<<<dim3(NBAGS, 2), 256, 0, stream>>>(FW, Wm, b, aggOut);
}

// Round 3
// 346.419 us; speedup vs baseline: 1.1197x; 1.1197x over previous
//
#include <hip/hip_runtime.h>
#include <hip/hip_bf16.h>

// Problem constants (fixed by setup_inputs)
#define N 8192
#define D 512
#define NBAGS 64
#define PER_BAG 128
#define TOPK 16

typedef float vfloat4 __attribute__((ext_vector_type(4)));

// ws layout (bytes):
//   invn    float[N]      @ 0       (32768)
//   keptIdx int[N*16]     @ 32768   (524288)
//   keptCnt int[N]        @ 557056  (32768)
//   deg     int[N]        @ 589824  (32768)
//   FW      float[64*512] @ 622592  (131072)
#define WS_INVN   0
#define WS_KIDX   32768
#define WS_KCNT   557056
#define WS_DEG    589824
#define WS_FW     622592

// Kernel 1: per-row inverse norm. 4 rows per 256-thread block.
// Blocks 0..31 also zero deg[]. (v5 form — v7's fused 256MB fill cost +44us
// serial; the fill is free when interleaved inside simtopk.)
__global__ void norm_kernel(const float* __restrict__ feat,
                            float* __restrict__ invn,
                            int* __restrict__ deg) {
    int t = threadIdx.x;
    if (blockIdx.x < 32) deg[blockIdx.x * 256 + t] = 0;
    int lane = t & 63, w = t >> 6;
    int r = blockIdx.x * 4 + w;
    const float4* fr = (const float4*)(feat + (size_t)r * D);
    float4 a = fr[lane];
    float4 bq = fr[lane + 64];
    float ss = a.x * a.x + a.y * a.y + a.z * a.z + a.w * a.w
             + bq.x * bq.x + bq.y * bq.y + bq.z * bq.z + bq.w * bq.w;
    #pragma unroll
    for (int off = 32; off > 0; off >>= 1) ss += __shfl_down(ss, off);
    if (lane == 0) invn[r] = 1.0f / fmaxf(sqrtf(ss), 1e-12f);
}

// Kernel 2 v8: sim + top-16 + adjacency fill, SOFTWARE-PIPELINED.
// R10 theory: v7 proved stores are free and the ~150us cost is the
// stage->barrier->compute->barrier lockstep exposing L2 latency every
// iteration. Fix: double-buffered LDS + register prefetch, ONE barrier
// per iteration. Iter it: prefetch chunk it+1 into regs (latency hides
// under compute), NT zero stores (v5 mapping, proven free), compute chunk
// it from buf[it&1], ds_write prefetch to buf[~it&1], barrier.
// Hazard-safe: writes to buf[p] in iter it+1 occur after the barrier that
// ends iter it, which guarantees all waves finished reading buf[p].
// LDS 36.9KB/block x4 blocks/CU = 147KB < 160KB.
__global__ __launch_bounds__(256, 4) void simtopk_kernel(
        const float* __restrict__ feat,
        const float* __restrict__ invn,
        float* __restrict__ adjOut,
        int* __restrict__ keptIdx,
        int* __restrict__ keptCnt,
        int* __restrict__ deg) {
    int rg = blockIdx.x;    // 0..15
    int bag = blockIdx.y;   // 0..63
    int t = threadIdx.x;    // 0..255
    __shared__ float colT[2][32][132];   // [buf][k][c]  (b128 reads)
    __shared__ float rowT[2][32][12];    // [buf][k][r]
    int bagBase = bag * PER_BAG;
    int rowBase = bagBase + rg * 8;
    int tx = t & 31;        // cols 4tx..4tx+3
    int ty = t >> 5;        // 0..7 -> row ty
    float4 acc = make_float4(0.f, 0.f, 0.f, 0.f);

    int kk = t & 31;
    int sub = t >> 5;       // 0..7
    // zero-store mapping: half a row per chunk (1024 f4), 4 f4/thread
    int winHalf = bag >> 5;          // which 1024-f4 half holds the window
    int jw = (bag & 31) >> 3;        // 256-f4 slab within that half
    int winLo = (bag & 31) * 32, winHi = winLo + 32;  // f4 cols within half
    vfloat4 zf4 = {0.f, 0.f, 0.f, 0.f};

    // prologue: stage chunk 0 into buffer 0
    #pragma unroll
    for (int c0 = 0; c0 < 16; ++c0)
        colT[0][kk][sub * 16 + c0] =
            feat[(size_t)(bagBase + sub * 16 + c0) * D + kk];
    rowT[0][kk][sub] = feat[(size_t)(rowBase + sub) * D + kk];
    __syncthreads();

    float pf[16], pr;
    for (int it = 0; it < 16; ++it) {
        int cur = it & 1;
        // prefetch chunk it+1 into regs (global loads issue, no wait here)
        if (it < 15) {
            int k0 = (it + 1) * 32;
            #pragma unroll
            for (int c0 = 0; c0 < 16; ++c0)
                pf[c0] = feat[(size_t)(bagBase + sub * 16 + c0) * D + k0 + kk];
            pr = feat[(size_t)(rowBase + sub) * D + k0 + kk];
        }
        // interleaved NT zero stores: row it>>1, half it&1 (drains under
        // compute + at barrier; v7 proved this is absorbed)
        {
            int zr = it >> 1, half = it & 1;
            vfloat4* rowp = (vfloat4*)(adjOut + (size_t)(rowBase + zr) * N)
                            + half * 1024;
            bool hasWin = (half == winHalf);
            #pragma unroll
            for (int j = 0; j < 4; ++j) {
                int f = t + 256 * j;
                if (hasWin && j == jw) {
                    if (f < winLo || f >= winHi)
                        __builtin_nontemporal_store(zf4, &rowp[f]);
                } else {
                    __builtin_nontemporal_store(zf4, &rowp[f]);
                }
            }
        }
        // compute current chunk from buf[cur] (hides prefetch latency)
        #pragma unroll
        for (int k = 0; k < 32; ++k) {
            float4 cv = *(const float4*)&colT[cur][k][4 * tx];
            float rv = rowT[cur][k][ty];
            acc.x += rv * cv.x; acc.y += rv * cv.y;
            acc.z += rv * cv.z; acc.w += rv * cv.w;
        }
        // write prefetch to the other buffer; single barrier
        if (it < 15) {
            int nxt = cur ^ 1;
            #pragma unroll
            for (int c0 = 0; c0 < 16; ++c0)
                colT[nxt][kk][sub * 16 + c0] = pf[c0];
            rowT[nxt][kk][sub] = pr;
        }
        __syncthreads();
    }
    // scale to cosine similarity
    float ic0 = invn[bagBase + 4 * tx];
    float ic1 = invn[bagBase + 4 * tx + 1];
    float ic2 = invn[bagBase + 4 * tx + 2];
    float ic3 = invn[bagBase + 4 * tx + 3];
    float ir = invn[rowBase + ty];
    acc.x *= ir * ic0; acc.y *= ir * ic1;
    acc.z *= ir * ic2; acc.w *= ir * ic3;

    // per-row top-16 within each half-wave (row ty);
    // 5-step shfl_xor butterfly, (val desc, idx asc) == lax.top_k tie-break
    {
        int r = rowBase + ty;
        float o0 = acc.x, o1 = acc.y, o2 = acc.z, o3 = acc.w;
        float w0 = o0, w1 = o1, w2 = o2, w3 = o3;
        int pm = 0, cnt = 0;
        #pragma unroll 1
        for (int itk = 0; itk < TOPK; ++itk) {
            float bv = w0; int bj = 0;
            if (w1 > bv) { bv = w1; bj = 1; }
            if (w2 > bv) { bv = w2; bj = 2; }
            if (w3 > bv) { bv = w3; bj = 3; }
            int bi = 4 * tx + bj;
            #pragma unroll
            for (int s = 1; s < 32; s <<= 1) {
                float ov = __shfl_xor(bv, s);
                int oi = __shfl_xor(bi, s);
                if (ov > bv || (ov == bv && oi < bi)) { bv = ov; bi = oi; }
            }
            if (bv <= 0.0f) break;   // uniform within half-wave
            if (tx == 0) keptIdx[(size_t)r * TOPK + cnt] = bi;
            cnt++;
            if ((bi >> 2) == tx) {
                pm |= 1 << (bi & 3);
                int q = bi & 3;
                if (q == 0) w0 = -1e30f;
                else if (q == 1) w1 = -1e30f;
                else if (q == 2) w2 = -1e30f;
                else w3 = -1e30f;
            }
        }
        if (tx == 0) keptCnt[r] = cnt;
        float4 ov4 = make_float4((pm & 1) ? o0 : 0.0f,
                                 (pm & 2) ? o1 : 0.0f,
                                 (pm & 4) ? o2 : 0.0f,
                                 (pm & 8) ? o3 : 0.0f);
        *(float4*)(adjOut + (size_t)r * N + bagBase + 4 * tx) = ov4;
        if (pm & 1) atomicAdd(&deg[bagBase + 4 * tx], 1);
        if (pm & 2) atomicAdd(&deg[bagBase + 4 * tx + 1], 1);
        if (pm & 4) atomicAdd(&deg[bagBase + 4 * tx + 2], 1);
        if (pm & 8) atomicAdd(&deg[bagBase + 4 * tx + 3], 1);
        int selfCol = rg * 8 + ty;
        if (tx == (selfCol >> 2) && !((pm >> (selfCol & 3)) & 1))
            atomicAdd(&deg[bagBase + selfCol], 1);
    }
}

// Kernel 3: w_r = dis[r]*sum_{c in C_r} dis[c]; FW[g,d] = sum_r w_r*feat[r,d]
// grid (64 bags, 4 d-chunks), 128 threads.
__global__ void wfw_kernel(const float* __restrict__ feat,
                           const int* __restrict__ keptIdx,
                           const int* __restrict__ keptCnt,
                           const int* __restrict__ deg,
                           float* __restrict__ FW) {
    int bag = blockIdx.x;
    int chunk = blockIdx.y;
    int t = threadIdx.x;            // 0..127
    __shared__ float wsh[PER_BAG];
    int bagBase = bag * PER_BAG;
    {
        int r = bagBase + t;
        int cnt = keptCnt[r];
        float sum = 0.0f;
        bool selfin = false;
        for (int k = 0; k < cnt; ++k) {
            int c = keptIdx[(size_t)r * TOPK + k];
            if (c == t) selfin = true;
            sum += rsqrtf((float)deg[bagBase + c]);
        }
        float disr = rsqrtf((float)deg[r]);
        if (!selfin) sum += disr;
        wsh[t] = disr * sum;
    }
    __syncthreads();
    int d = chunk * 128 + t;
    float acc = 0.0f;
    #pragma unroll 8
    for (int r = 0; r < PER_BAG; ++r)
        acc += wsh[r] * feat[(size_t)(bagBase + r) * D + d];
    FW[bag * D + d] = acc;
}

// Kernel 4: agg = FW @ W + 128*b.  grid (64, 2), 256 threads.
__global__ void agg_kernel(const float* __restrict__ FW,
                           const float* __restrict__ Wm,
                           const float* __restrict__ b,
                           float* __restrict__ aggOut) {
    int bag = blockIdx.x;
    int chunk = blockIdx.y;
    int t = threadIdx.x;
    __shared__ float fws[D];
    fws[t] = FW[bag * D + t];
    fws[256 + t] = FW[bag * D + 256 + t];
    __syncthreads();
    int d = chunk * 256 + t;
    float acc = 0.0f;
    #pragma unroll 8
    for (int k = 0; k < D; ++k)
        acc += fws[k] * Wm[(size_t)k * D + d];
    aggOut[bag * D + d] = acc + 128.0f * b[d];
}

extern "C" void kernel_launch(void* const* d_in, const int* in_sizes, int n_in,
                              void* d_out, int out_size, void* d_ws, size_t ws_size,
                              hipStream_t stream) {
    const float* feat = (const float*)d_in[0];
    const float* Wm   = (const float*)d_in[1];
    const float* b    = (const float*)d_in[2];
    // d_in[3] = batch (structure hardcoded: 64 contiguous bags x 128)
    // d_in[4] = n_topk (16), d_in[5] = n_bags (64)

    char* ws = (char*)d_ws;
    float* invn   = (float*)(ws + WS_INVN);
    int* keptIdx  = (int*)(ws + WS_KIDX);
    int* keptCnt  = (int*)(ws + WS_KCNT);
    int* deg      = (int*)(ws + WS_DEG);
    float* FW     = (float*)(ws + WS_FW);

    float* aggOut = (float*)d_out;                    // [64*512]
    float* adjOut = (float*)d_out + NBAGS * D;        // [8192*8192]

    norm_kernel<<<N / 4, 256, 0, stream>>>(feat, invn, deg);
    simtopk_kernel<<<dim3(16, NBAGS), 256, 0, stream>>>(feat, invn, adjOut,
                                                        keptIdx, keptCnt, deg);
    wfw_kernel<<<dim3(NBAGS, 4), PER_BAG, 0, stream>>>(feat, keptIdx, keptCnt,
                                                       deg, FW);
    agg_kernel<<<dim3(NBAGS, 2), 256, 0, stream>>>(FW, Wm, b, aggOut);
}